// Round 1
// 960.451 us; speedup vs baseline: 1.0087x; 1.0087x over previous
//
#include <hip/hip_runtime.h>
#include <math.h>

#define BS 256
#define HID 1024
#define ACT 16
#define MEM_DIM 512
#define NUM_MEM 1024
#define MEM_H 32

// ---- d_out layout (floats): read_v, other_v, M_new, alpha ----
#define OUT_READV 0
#define OUT_OTHER (BS * MEM_DIM)
#define OUT_MNEW  (2 * BS * MEM_DIM)
#define OUT_ALPHA (2 * BS * MEM_DIM + (size_t)BS * NUM_MEM * MEM_DIM)

// ---- ws layout (floats) ----
#define WS_ERASE 0
#define WS_ADD   (BS * MEM_DIM)
#define WS_G1    (2 * BS * MEM_DIM)

typedef float v4f __attribute__((ext_vector_type(4)));

__device__ __forceinline__ float sigmoidf_(float x) { return 1.f / (1.f + expf(-x)); }
__device__ __forceinline__ float leakyf_(float x) { return x > 0.f ? x : 0.2f * x; }

// ---------------------------------------------------------------------------
// Kernel 1: fused f32 GEMM  C = h(256x1024) @ [Wv(1024x1536) | Wg1(1024x512)]
// tile 32x64, Kc=32, 256 threads, each thread 2x4 accumulators.
// epilogue: seg0 sigmoid->ws_erase, seg1 raw->ws_add, seg2 raw->out_other,
//           seg3 leaky->ws_g1            (unchanged from verified version)
// ---------------------------------------------------------------------------
#define TM 32
#define TN 64
#define KC 32

__global__ __launch_bounds__(256) void gemm_fused_kernel(
    const float* __restrict__ h, const float* __restrict__ Wv,
    const float* __restrict__ Wg1, const float* __restrict__ bv,
    const float* __restrict__ bg1, float* __restrict__ ws,
    float* __restrict__ out_other)
{
    __shared__ float As[KC][TM + 1];   // [k][m]
    __shared__ float Bs[KC][TN + 4];   // [k][n]
    int tid = threadIdx.x;
    int n0 = blockIdx.x * TN;          // 0..2047 (tile never straddles 512-seg)
    int m0 = blockIdx.y * TM;
    int tc = tid & 15, tr = tid >> 4;

    float acc[2][4];
    #pragma unroll
    for (int j = 0; j < 2; ++j)
        #pragma unroll
        for (int i = 0; i < 4; ++i) acc[j][i] = 0.f;

    int a_m  = tid >> 3;           // 0..31
    int a_k4 = (tid & 7) * 4;      // 0..28
    int b_n4 = (tid & 15) * 4;     // 0..60
    int b_k  = tid >> 4;           // 0..15
    const bool isWv = (n0 < 3 * MEM_DIM);

    for (int k0 = 0; k0 < HID; k0 += KC) {
        float4 av4 = *(const float4*)&h[(size_t)(m0 + a_m) * HID + k0 + a_k4];
        As[a_k4 + 0][a_m] = av4.x;
        As[a_k4 + 1][a_m] = av4.y;
        As[a_k4 + 2][a_m] = av4.z;
        As[a_k4 + 3][a_m] = av4.w;
        #pragma unroll
        for (int p = 0; p < 2; ++p) {
            int kk = b_k + p * 16;
            float4 bv4;
            if (isWv)
                bv4 = *(const float4*)&Wv[(size_t)(k0 + kk) * (3 * MEM_DIM) + n0 + b_n4];
            else
                bv4 = *(const float4*)&Wg1[(size_t)(k0 + kk) * MEM_DIM + (n0 - 3 * MEM_DIM) + b_n4];
            *(float4*)&Bs[kk][b_n4] = bv4;
        }
        __syncthreads();
        #pragma unroll
        for (int k = 0; k < KC; ++k) {
            float a0 = As[k][tr * 2 + 0];
            float a1 = As[k][tr * 2 + 1];
            float4 b4 = *(float4*)&Bs[k][tc * 4];
            acc[0][0] += a0 * b4.x; acc[0][1] += a0 * b4.y;
            acc[0][2] += a0 * b4.z; acc[0][3] += a0 * b4.w;
            acc[1][0] += a1 * b4.x; acc[1][1] += a1 * b4.y;
            acc[1][2] += a1 * b4.z; acc[1][3] += a1 * b4.w;
        }
        __syncthreads();
    }

    int seg = n0 >> 9;   // 0,1,2 -> Wv cols; 3 -> Wg1 cols
    #pragma unroll
    for (int j = 0; j < 2; ++j) {
        int r = m0 + tr * 2 + j;
        #pragma unroll
        for (int i = 0; i < 4; ++i) {
            int c = n0 + tc * 4 + i;
            float v = acc[j][i];
            if (seg < 3) v += bv[c]; else v += bg1[c - 3 * MEM_DIM];
            if (seg == 0)      ws[WS_ERASE + r * MEM_DIM + c]               = sigmoidf_(v);
            else if (seg == 1) ws[WS_ADD   + r * MEM_DIM + (c - MEM_DIM)]   = v;
            else if (seg == 2) out_other[r * MEM_DIM + (c - 2 * MEM_DIM)]   = v;
            else               ws[WS_G1    + r * MEM_DIM + (c - 3 * MEM_DIM)] = leakyf_(v);
        }
    }
}

// ---------------------------------------------------------------------------
// Kernel 2: fully fused  knet + gate + dyn-conv + memory update + read_v.
// grid (b=256, dc=4): each block owns d-chunk [dc*128, dc*128+128) across ALL
// 1024 memory slots -> read_v is a per-thread register accumulation + one LDS
// tree reduce.  No atomics, no memset, no alpha round-trip through HBM.
// Prologue (redundant per dc, cheap):
//   wave 0: kernel-net (orig + argmax-flip) -> softmax -> ksh[9]
//   wave 1: gate = sigmoid(g1 . Wg2 + bg2)  -> gsh
//   waves 2-3: prev_alpha -> LDS pa[1024]
//   all: 3x3 SAME conv + gate blend -> LDS al[1024]  (dc==0 writes out_alpha)
// Main: stream M -> M_new nontemporally, acc += alpha*M_new.
// ---------------------------------------------------------------------------
__global__ __launch_bounds__(256) void update_fused_kernel(
    const float* __restrict__ a, const float* __restrict__ Wk1,
    const float* __restrict__ bk1, const float* __restrict__ Wk2,
    const float* __restrict__ bk2,
    const float* __restrict__ prev_alpha,
    const float* __restrict__ g1, const float* __restrict__ Wg2,
    const float* __restrict__ bg2,
    const float* __restrict__ M,
    const float* __restrict__ erase, const float* __restrict__ add,
    float* __restrict__ M_new, float* __restrict__ read_v,
    float* __restrict__ alpha_out)
{
    int b  = blockIdx.x;
    int dc = blockIdx.y;
    int t  = threadIdx.x;

    __shared__ __align__(16) float pa[NUM_MEM];   // prev_alpha; reused as read_v reduce buf
    __shared__ __align__(16) float al[NUM_MEM];   // blended alpha
    __shared__ float ksh[9];
    __shared__ float gsh;

    // issue the per-chunk erase/add loads early (independent of prologue)
    int dl = (t & 31) * 4;
    int d  = dc * 128 + dl;
    v4f e  = *(const v4f*)(erase + b * MEM_DIM + d);
    v4f ad = *(const v4f*)(add   + b * MEM_DIM + d);

    if (t < 64) {
        // ---- wave 0: kernel-net (identical math to verified knet_kernel) ----
        float as_[ACT];
        #pragma unroll
        for (int j = 0; j < ACT; ++j) as_[j] = a[b * ACT + j];
        float mx = as_[1];
        #pragma unroll
        for (int j = 2; j < ACT; ++j) mx = fmaxf(mx, as_[j]);
        bool m = as_[0] >= mx;      // argmax(a)==0 (ties -> first index)

        float po[9], pn[9];
        #pragma unroll
        for (int o = 0; o < 9; ++o) { po[o] = 0.f; pn[o] = 0.f; }

        #pragma unroll
        for (int i = 0; i < 8; ++i) {
            int u = t + 64 * i;
            float so = bk1[u], sn = bk1[u];
            #pragma unroll
            for (int j = 0; j < ACT; ++j) {
                float w  = Wk1[j * MEM_DIM + u];
                float av = as_[j];
                float avn = (j == 0) ? (m ? 0.f : av)
                          : (j == 1) ? (m ? 1.f : av) : av;
                so += av * w;
                sn += avn * w;
            }
            so = leakyf_(so);
            sn = leakyf_(sn);
            #pragma unroll
            for (int o = 0; o < 9; ++o) {
                float w2 = Wk2[u * 9 + o];
                po[o] += so * w2;
                pn[o] += sn * w2;
            }
        }
        #pragma unroll
        for (int off = 32; off; off >>= 1) {
            #pragma unroll
            for (int o = 0; o < 9; ++o) {
                po[o] += __shfl_down(po[o], off, 64);
                pn[o] += __shfl_down(pn[o], off, 64);
            }
        }
        if (t == 0) {
            float k[9];
            #pragma unroll
            for (int o = 0; o < 9; ++o) {
                float ko = po[o] + bk2[o];
                float kn = pn[8 - o] + bk2[8 - o];   // spatial flip
                k[o] = m ? kn : ko;
            }
            float kmax = k[0];
            #pragma unroll
            for (int o = 1; o < 9; ++o) kmax = fmaxf(kmax, k[o]);
            float s = 0.f;
            #pragma unroll
            for (int o = 0; o < 9; ++o) { k[o] = expf(k[o] - kmax); s += k[o]; }
            float inv = 1.f / s;
            #pragma unroll
            for (int o = 0; o < 9; ++o) ksh[o] = k[o] * inv;
        }
    } else if (t < 128) {
        // ---- wave 1: gate dot product, 8 strided elements per lane ----
        int l = t - 64;
        float p = 0.f;
        #pragma unroll
        for (int k = 0; k < 8; ++k)
            p += g1[b * MEM_DIM + l + 64 * k] * Wg2[l + 64 * k];
        #pragma unroll
        for (int off = 32; off; off >>= 1) p += __shfl_down(p, off, 64);
        if (l == 0) gsh = sigmoidf_(p + bg2[0]);
    } else {
        // ---- waves 2-3: stage prev_alpha -> LDS ----
        int i0 = (t - 128) * 8;
        *(float4*)&pa[i0]     = *(const float4*)&prev_alpha[(size_t)b * NUM_MEM + i0];
        *(float4*)&pa[i0 + 4] = *(const float4*)&prev_alpha[(size_t)b * NUM_MEM + i0 + 4];
    }
    __syncthreads();

    // ---- all threads: 3x3 SAME cross-correlation + gate blend ----
    float gate = gsh;
    v4f outv;
    #pragma unroll
    for (int q = 0; q < 4; ++q) {
        int c = t * 4 + q;
        int i = c >> 5, j = c & 31;
        float s = 0.f;
        #pragma unroll
        for (int ki = 0; ki < 3; ++ki) {
            int ii = i + ki - 1;
            if (ii < 0 || ii >= MEM_H) continue;
            #pragma unroll
            for (int kj = 0; kj < 3; ++kj) {
                int jj = j + kj - 1;
                if (jj < 0 || jj >= MEM_H) continue;
                s += pa[ii * MEM_H + jj] * ksh[ki * 3 + kj];
            }
        }
        float v = s * gate + pa[c] * (1.f - gate);
        al[c] = v;
        outv[q] = v;
    }
    if (dc == 0)
        *(v4f*)&alpha_out[(size_t)b * NUM_MEM + t * 4] = outv;
    __syncthreads();

    // ---- streaming update over all 1024 slots, this block's 128-float d-chunk
    // half-wave (32 lanes) covers a contiguous 512B row segment; each thread
    // owns a contiguous band of 128 rows.
    const float* Mb = M     + (size_t)b * NUM_MEM * MEM_DIM + d;
    float*       Ob = M_new + (size_t)b * NUM_MEM * MEM_DIM + d;
    const float* alp = &al[(t >> 5) * 128];
    Mb += (size_t)(t >> 5) * 128 * MEM_DIM;
    Ob += (size_t)(t >> 5) * 128 * MEM_DIM;

    v4f acc = 0.f;
    #pragma unroll 8
    for (int i = 0; i < 128; ++i) {
        float av = alp[i];
        v4f m4 = __builtin_nontemporal_load((const v4f*)(Mb + (size_t)i * MEM_DIM));
        v4f mn = m4 * (1.f - av * e) + av * ad;
        __builtin_nontemporal_store(mn, (v4f*)(Ob + (size_t)i * MEM_DIM));
        acc += av * mn;
    }

    // ---- read_v: reduce the 8 thread-bands sharing each d (reuse pa as buf)
    *(v4f*)&pa[t * 4] = acc;
    __syncthreads();
    if (t < 32) {
        v4f s = *(v4f*)&pa[t * 4];
        #pragma unroll
        for (int j = 1; j < 8; ++j) s += *(v4f*)&pa[(t + 32 * j) * 4];
        *(v4f*)(read_v + (size_t)b * MEM_DIM + dc * 128 + t * 4) = s;
    }
}

// ---------------------------------------------------------------------------
extern "C" void kernel_launch(void* const* d_in, const int* in_sizes, int n_in,
                              void* d_out, int out_size, void* d_ws, size_t ws_size,
                              hipStream_t stream)
{
    const float* h          = (const float*)d_in[0];
    const float* a          = (const float*)d_in[1];
    // d_in[2] = prev_h (unused by the reference)
    const float* prev_alpha = (const float*)d_in[3];
    const float* M          = (const float*)d_in[4];
    const float* Wv         = (const float*)d_in[5];
    const float* bv         = (const float*)d_in[6];
    const float* Wk1        = (const float*)d_in[7];
    const float* bk1        = (const float*)d_in[8];
    const float* Wk2        = (const float*)d_in[9];
    const float* bk2        = (const float*)d_in[10];
    const float* Wg1        = (const float*)d_in[11];
    const float* bg1        = (const float*)d_in[12];
    const float* Wg2        = (const float*)d_in[13];
    const float* bg2        = (const float*)d_in[14];

    float* out = (float*)d_out;
    float* ws  = (float*)d_ws;

    float* out_readv = out + OUT_READV;
    float* out_other = out + OUT_OTHER;
    float* out_mnew  = out + OUT_MNEW;
    float* out_alpha = out + OUT_ALPHA;

    gemm_fused_kernel<<<dim3(2048 / TN, BS / TM), 256, 0, stream>>>(
        h, Wv, Wg1, bv, bg1, ws, out_other);

    update_fused_kernel<<<dim3(BS, 4), 256, 0, stream>>>(
        a, Wk1, bk1, Wk2, bk2, prev_alpha,
        ws + WS_G1, Wg2, bg2, M,
        ws + WS_ERASE, ws + WS_ADD,
        out_mnew, out_readv, out_alpha);
}

// Round 2
// 931.546 us; speedup vs baseline: 1.0400x; 1.0310x over previous
//
#include <hip/hip_runtime.h>
#include <math.h>

#define BS 256
#define HID 1024
#define ACT 16
#define MEM_DIM 512
#define NUM_MEM 1024
#define MEM_H 32

// ---- d_out layout (floats): read_v, other_v, M_new, alpha ----
#define OUT_READV 0
#define OUT_OTHER (BS * MEM_DIM)
#define OUT_MNEW  (2 * BS * MEM_DIM)
#define OUT_ALPHA (2 * BS * MEM_DIM + (size_t)BS * NUM_MEM * MEM_DIM)

// ---- ws layout (floats) ----
#define WS_ERASE 0
#define WS_ADD   (BS * MEM_DIM)
#define WS_G1    (2 * BS * MEM_DIM)

typedef float v4f __attribute__((ext_vector_type(4)));

__device__ __forceinline__ float sigmoidf_(float x) { return 1.f / (1.f + expf(-x)); }
__device__ __forceinline__ float leakyf_(float x) { return x > 0.f ? x : 0.2f * x; }

// ---------------------------------------------------------------------------
// Kernel 1: fused f32 GEMM  C = h(256x1024) @ [Wv(1024x1536) | Wg1(1024x512)]
// tile 32x64, Kc=32, 256 threads, each thread 2x4 accumulators.
// epilogue: seg0 sigmoid->ws_erase, seg1 raw->ws_add, seg2 raw->out_other,
//           seg3 leaky->ws_g1            (unchanged, verified)
// ---------------------------------------------------------------------------
#define TM 32
#define TN 64
#define KC 32

__global__ __launch_bounds__(256) void gemm_fused_kernel(
    const float* __restrict__ h, const float* __restrict__ Wv,
    const float* __restrict__ Wg1, const float* __restrict__ bv,
    const float* __restrict__ bg1, float* __restrict__ ws,
    float* __restrict__ out_other)
{
    __shared__ float As[KC][TM + 1];   // [k][m]
    __shared__ float Bs[KC][TN + 4];   // [k][n]
    int tid = threadIdx.x;
    int n0 = blockIdx.x * TN;          // 0..2047 (tile never straddles 512-seg)
    int m0 = blockIdx.y * TM;
    int tc = tid & 15, tr = tid >> 4;

    float acc[2][4];
    #pragma unroll
    for (int j = 0; j < 2; ++j)
        #pragma unroll
        for (int i = 0; i < 4; ++i) acc[j][i] = 0.f;

    int a_m  = tid >> 3;           // 0..31
    int a_k4 = (tid & 7) * 4;      // 0..28
    int b_n4 = (tid & 15) * 4;     // 0..60
    int b_k  = tid >> 4;           // 0..15
    const bool isWv = (n0 < 3 * MEM_DIM);

    for (int k0 = 0; k0 < HID; k0 += KC) {
        float4 av4 = *(const float4*)&h[(size_t)(m0 + a_m) * HID + k0 + a_k4];
        As[a_k4 + 0][a_m] = av4.x;
        As[a_k4 + 1][a_m] = av4.y;
        As[a_k4 + 2][a_m] = av4.z;
        As[a_k4 + 3][a_m] = av4.w;
        #pragma unroll
        for (int p = 0; p < 2; ++p) {
            int kk = b_k + p * 16;
            float4 bv4;
            if (isWv)
                bv4 = *(const float4*)&Wv[(size_t)(k0 + kk) * (3 * MEM_DIM) + n0 + b_n4];
            else
                bv4 = *(const float4*)&Wg1[(size_t)(k0 + kk) * MEM_DIM + (n0 - 3 * MEM_DIM) + b_n4];
            *(float4*)&Bs[kk][b_n4] = bv4;
        }
        __syncthreads();
        #pragma unroll
        for (int k = 0; k < KC; ++k) {
            float a0 = As[k][tr * 2 + 0];
            float a1 = As[k][tr * 2 + 1];
            float4 b4 = *(float4*)&Bs[k][tc * 4];
            acc[0][0] += a0 * b4.x; acc[0][1] += a0 * b4.y;
            acc[0][2] += a0 * b4.z; acc[0][3] += a0 * b4.w;
            acc[1][0] += a1 * b4.x; acc[1][1] += a1 * b4.y;
            acc[1][2] += a1 * b4.z; acc[1][3] += a1 * b4.w;
        }
        __syncthreads();
    }

    int seg = n0 >> 9;   // 0,1,2 -> Wv cols; 3 -> Wg1 cols
    #pragma unroll
    for (int j = 0; j < 2; ++j) {
        int r = m0 + tr * 2 + j;
        #pragma unroll
        for (int i = 0; i < 4; ++i) {
            int c = n0 + tc * 4 + i;
            float v = acc[j][i];
            if (seg < 3) v += bv[c]; else v += bg1[c - 3 * MEM_DIM];
            if (seg == 0)      ws[WS_ERASE + r * MEM_DIM + c]               = sigmoidf_(v);
            else if (seg == 1) ws[WS_ADD   + r * MEM_DIM + (c - MEM_DIM)]   = v;
            else if (seg == 2) out_other[r * MEM_DIM + (c - 2 * MEM_DIM)]   = v;
            else               ws[WS_G1    + r * MEM_DIM + (c - 3 * MEM_DIM)] = leakyf_(v);
        }
    }
}

// ---------------------------------------------------------------------------
// Kernel 2: fully fused  knet + gate + dyn-conv + memory update + read_v.
// grid (b=256), 512 threads. Each block owns ALL 1024 rows x full 512 d of
// batch b -> read_v stays register-local (no atomics, no memset).
// Streaming layout: thread t -> d=(t&127)*4, row-group g=t>>7 walks rows
// g, g+4, g+8, ... : every 128-thread group reads/writes a FULL contiguous
// 2KB row, groups interleave rows mod 4 -> sequential DRAM walk per CU
// (this is the round-1 fix: the dc-split's 512B@2KB-stride pattern lost
// DRAM page locality and gave back ~20us).
// Prologue:
//   wave 0: kernel-net (orig + argmax-flip) -> softmax -> ksh[9]
//   wave 1: gate = sigmoid(g1 . Wg2 + bg2)  -> gsh
//   waves 2-3: prev_alpha -> LDS pa[1024]
//   waves 4-7: idle (~2us, hidden)
//   t<256: 3x3 SAME conv + gate blend -> LDS al[1024], write out_alpha
// ---------------------------------------------------------------------------
__global__ __launch_bounds__(512) void update_fused_kernel(
    const float* __restrict__ a, const float* __restrict__ Wk1,
    const float* __restrict__ bk1, const float* __restrict__ Wk2,
    const float* __restrict__ bk2,
    const float* __restrict__ prev_alpha,
    const float* __restrict__ g1, const float* __restrict__ Wg2,
    const float* __restrict__ bg2,
    const float* __restrict__ M,
    const float* __restrict__ erase, const float* __restrict__ add,
    float* __restrict__ M_new, float* __restrict__ read_v,
    float* __restrict__ alpha_out)
{
    int b = blockIdx.x;
    int t = threadIdx.x;

    __shared__ __align__(16) float pa[NUM_MEM];   // prev_alpha; reused as reduce buf (grp 0-1)
    __shared__ __align__(16) float al[NUM_MEM];   // blended alpha; reused as reduce buf (grp 2-3)
    __shared__ float ksh[9];
    __shared__ float gsh;

    // issue the per-thread erase/add loads early (independent of prologue)
    int d = (t & 127) * 4;
    v4f e  = *(const v4f*)(erase + b * MEM_DIM + d);
    v4f ad = *(const v4f*)(add   + b * MEM_DIM + d);

    if (t < 64) {
        // ---- wave 0: kernel-net (identical math to verified knet_kernel) ----
        float as_[ACT];
        #pragma unroll
        for (int j = 0; j < ACT; ++j) as_[j] = a[b * ACT + j];
        float mx = as_[1];
        #pragma unroll
        for (int j = 2; j < ACT; ++j) mx = fmaxf(mx, as_[j]);
        bool m = as_[0] >= mx;      // argmax(a)==0 (ties -> first index)

        float po[9], pn[9];
        #pragma unroll
        for (int o = 0; o < 9; ++o) { po[o] = 0.f; pn[o] = 0.f; }

        #pragma unroll
        for (int i = 0; i < 8; ++i) {
            int u = t + 64 * i;
            float so = bk1[u], sn = bk1[u];
            #pragma unroll
            for (int j = 0; j < ACT; ++j) {
                float w  = Wk1[j * MEM_DIM + u];
                float av = as_[j];
                float avn = (j == 0) ? (m ? 0.f : av)
                          : (j == 1) ? (m ? 1.f : av) : av;
                so += av * w;
                sn += avn * w;
            }
            so = leakyf_(so);
            sn = leakyf_(sn);
            #pragma unroll
            for (int o = 0; o < 9; ++o) {
                float w2 = Wk2[u * 9 + o];
                po[o] += so * w2;
                pn[o] += sn * w2;
            }
        }
        #pragma unroll
        for (int off = 32; off; off >>= 1) {
            #pragma unroll
            for (int o = 0; o < 9; ++o) {
                po[o] += __shfl_down(po[o], off, 64);
                pn[o] += __shfl_down(pn[o], off, 64);
            }
        }
        if (t == 0) {
            float k[9];
            #pragma unroll
            for (int o = 0; o < 9; ++o) {
                float ko = po[o] + bk2[o];
                float kn = pn[8 - o] + bk2[8 - o];   // spatial flip
                k[o] = m ? kn : ko;
            }
            float kmax = k[0];
            #pragma unroll
            for (int o = 1; o < 9; ++o) kmax = fmaxf(kmax, k[o]);
            float s = 0.f;
            #pragma unroll
            for (int o = 0; o < 9; ++o) { k[o] = expf(k[o] - kmax); s += k[o]; }
            float inv = 1.f / s;
            #pragma unroll
            for (int o = 0; o < 9; ++o) ksh[o] = k[o] * inv;
        }
    } else if (t < 128) {
        // ---- wave 1: gate dot product, 8 strided elements per lane ----
        int l = t - 64;
        float p = 0.f;
        #pragma unroll
        for (int k = 0; k < 8; ++k)
            p += g1[b * MEM_DIM + l + 64 * k] * Wg2[l + 64 * k];
        #pragma unroll
        for (int off = 32; off; off >>= 1) p += __shfl_down(p, off, 64);
        if (l == 0) gsh = sigmoidf_(p + bg2[0]);
    } else if (t < 256) {
        // ---- waves 2-3: stage prev_alpha -> LDS ----
        int i0 = (t - 128) * 8;
        *(float4*)&pa[i0]     = *(const float4*)&prev_alpha[(size_t)b * NUM_MEM + i0];
        *(float4*)&pa[i0 + 4] = *(const float4*)&prev_alpha[(size_t)b * NUM_MEM + i0 + 4];
    }
    __syncthreads();

    // ---- t<256: 3x3 SAME cross-correlation + gate blend ----
    float gate = gsh;
    if (t < 256) {
        v4f outv;
        #pragma unroll
        for (int q = 0; q < 4; ++q) {
            int c = t * 4 + q;
            int i = c >> 5, j = c & 31;
            float s = 0.f;
            #pragma unroll
            for (int ki = 0; ki < 3; ++ki) {
                int ii = i + ki - 1;
                if (ii < 0 || ii >= MEM_H) continue;
                #pragma unroll
                for (int kj = 0; kj < 3; ++kj) {
                    int jj = j + kj - 1;
                    if (jj < 0 || jj >= MEM_H) continue;
                    s += pa[ii * MEM_H + jj] * ksh[ki * 3 + kj];
                }
            }
            float v = s * gate + pa[c] * (1.f - gate);
            al[c] = v;
            outv[q] = v;
        }
        *(v4f*)&alpha_out[(size_t)b * NUM_MEM + t * 4] = outv;
    }
    __syncthreads();

    // ---- streaming update: all 1024 rows, full d per 128-thread group ----
    int g = t >> 7;   // row-group 0..3; rows g, g+4, g+8, ...
    const float* Mb = M     + (size_t)b * NUM_MEM * MEM_DIM + (size_t)g * MEM_DIM + d;
    float*       Ob = M_new + (size_t)b * NUM_MEM * MEM_DIM + (size_t)g * MEM_DIM + d;

    v4f acc = 0.f;
    #pragma unroll 8
    for (int i = 0; i < 256; ++i) {
        float av = al[g + i * 4];                 // wave-uniform -> LDS broadcast
        v4f m4 = __builtin_nontemporal_load((const v4f*)(Mb + (size_t)i * 4 * MEM_DIM));
        v4f mn = m4 * (1.f - av * e) + av * ad;
        __builtin_nontemporal_store(mn, (v4f*)(Ob + (size_t)i * 4 * MEM_DIM));
        acc += av * mn;
    }

    // ---- read_v: reduce the 4 row-group partials (reuse pa/al as buffers) ----
    __syncthreads();                              // al still being read above
    if (t < 256) *(v4f*)&pa[t * 4]         = acc;
    else         *(v4f*)&al[(t - 256) * 4] = acc;
    __syncthreads();
    if (t < 128) {
        v4f s = *(v4f*)&pa[t * 4] + *(v4f*)&pa[(t + 128) * 4]
              + *(v4f*)&al[t * 4] + *(v4f*)&al[(t + 128) * 4];
        *(v4f*)(read_v + (size_t)b * MEM_DIM + t * 4) = s;
    }
}

// ---------------------------------------------------------------------------
extern "C" void kernel_launch(void* const* d_in, const int* in_sizes, int n_in,
                              void* d_out, int out_size, void* d_ws, size_t ws_size,
                              hipStream_t stream)
{
    const float* h          = (const float*)d_in[0];
    const float* a          = (const float*)d_in[1];
    // d_in[2] = prev_h (unused by the reference)
    const float* prev_alpha = (const float*)d_in[3];
    const float* M          = (const float*)d_in[4];
    const float* Wv         = (const float*)d_in[5];
    const float* bv         = (const float*)d_in[6];
    const float* Wk1        = (const float*)d_in[7];
    const float* bk1        = (const float*)d_in[8];
    const float* Wk2        = (const float*)d_in[9];
    const float* bk2        = (const float*)d_in[10];
    const float* Wg1        = (const float*)d_in[11];
    const float* bg1        = (const float*)d_in[12];
    const float* Wg2        = (const float*)d_in[13];
    const float* bg2        = (const float*)d_in[14];

    float* out = (float*)d_out;
    float* ws  = (float*)d_ws;

    float* out_readv = out + OUT_READV;
    float* out_other = out + OUT_OTHER;
    float* out_mnew  = out + OUT_MNEW;
    float* out_alpha = out + OUT_ALPHA;

    gemm_fused_kernel<<<dim3(2048 / TN, BS / TM), 256, 0, stream>>>(
        h, Wv, Wg1, bv, bg1, ws, out_other);

    update_fused_kernel<<<BS, 512, 0, stream>>>(
        a, Wk1, bk1, Wk2, bk2, prev_alpha,
        ws + WS_G1, Wg2, bg2, M,
        ws + WS_ERASE, ws + WS_ADD,
        out_mnew, out_readv, out_alpha);
}